// Round 5
// baseline (186.064 us; speedup 1.0000x reference)
//
#include <hip/hip_runtime.h>
#include <hip/hip_bf16.h>
#include <hip/hip_fp8.h>

#define N_ROWS 8192
#define NZ 16384           // rows of Z = [An; Bn]
#define DIM 256
#define TAU_INV 2.0f
#define BT 128             // col tile width
#define AT 64              // row tile height (A strip)
#define NTILE 128          // NZ / BT  (col tiles)
#define NCHUNK 16
#define SEGT 4             // col tiles per segment
#define NSEG 4224          // sum over ri of ceil((128 - (ri>>1))/4)
#define PSTRIDE 768        // floats/segment: 4*64 row-partials + 4*128 col-partials

typedef float f32x4 __attribute__((ext_vector_type(4)));
typedef long lx2 __attribute__((ext_vector_type(2)));   // 16B = 2 fp8 MFMA operands

// ---------------------------------------------------------------------------
// Kernel 1: one WAVE per row. L2-normalize, scale by 16, quantize to OCP fp8
// e4m3, write Z8 K-INTERLEAVED: each 64B chunk stores its eight 8B K-groups
// as [g0 g4 g1 g5 g2 g6 g3 g7] so one 16B granule = operand pair (g, g+4)
// for two consecutive MFMA K-steps. pos[i] = (1/256)*dot(quantized an, bn).
// ---------------------------------------------------------------------------
__global__ __launch_bounds__(256) void normalize_kernel(
    const float* __restrict__ z1, const float* __restrict__ z2,
    unsigned char* __restrict__ Z8, float* __restrict__ pos)
{
    const int tid = threadIdx.x;
    const int wave = tid >> 6;
    const int lane = tid & 63;
    const int row = blockIdx.x * 4 + wave;      // 0..8191

    const float4 a = ((const float4*)(z1 + (size_t)row * DIM))[lane];
    const float4 b = ((const float4*)(z2 + (size_t)row * DIM))[lane];

    auto wsum = [&](float v) -> float {
        #pragma unroll
        for (int m = 1; m < 64; m <<= 1) v += __shfl_xor(v, m, 64);
        return v;
    };

    const float na2 = wsum(a.x*a.x + a.y*a.y + a.z*a.z + a.w*a.w);
    const float nb2 = wsum(b.x*b.x + b.y*b.y + b.z*b.z + b.w*b.w);
    const float sa = 16.0f / sqrtf(na2);   // norms ~16; eps never binds
    const float sb = 16.0f / sqrtf(nb2);

    const float av[4] = {a.x*sa, a.y*sa, a.z*sa, a.w*sa};
    const float bv[4] = {b.x*sb, b.y*sb, b.z*sb, b.w*sb};
    unsigned char pa[4], pb[4];
    float qd = 0.0f;
    #pragma unroll
    for (int k = 0; k < 4; ++k) {
        __hip_fp8_e4m3 qa(av[k]);
        __hip_fp8_e4m3 qb(bv[k]);
        pa[k] = qa.__x; pb[k] = qb.__x;
        qd += float(qa) * float(qb);
    }
    const int g  = (lane >> 1) & 7;
    const int pp = ((g & 3) << 1) | (g >> 2);          // interleaved 8B slot
    const int off = (lane >> 4) * 64 + pp * 8 + (lane & 1) * 4;
    *(uchar4*)(Z8 + (size_t)row * DIM + off) = *(uchar4*)pa;
    *(uchar4*)(Z8 + (size_t)(N_ROWS + row) * DIM + off) = *(uchar4*)pb;

    qd = wsum(qd);
    if (lane == 0) pos[row] = qd * 0.00390625f;   // /256 -> quantized sim
}

// ---------------------------------------------------------------------------
// Kernel 2: symmetric fp8 gram, upper triangle, 64x128 tiles, STRIP-SEGMENTED,
// ALL-REGISTER / BARRIER-FREE (R5). R4 lesson: with A in regs, the residual
// cost was the two __syncthreads() vmcnt(0) drains per tile that exist only
// to route B through LDS. But fragments load straight from global: lane
// (lm,lq) reads 16B at row(lm)*256 + kh*128 + set*64 + lq*16, and a wave's
// 64 addresses form 16 dense aligned 64B lines per instruction — perfectly
// coalesced, L2-resident (Z8 = 4MB). So: NO LDS, NO barriers, waves run
// free; occupancy VGPR-limited (launch_bounds(256,3) -> 12 waves/CU whose
// aggregate MFMA demand saturates the matrix pipe).
// Wave layout 1x4: wave w owns all 64 A rows x cols w*32..w*32+31. B (the
// streamed operand) has ZERO inter-wave duplication; A (reused across the
// segment) duplicates x4 at +48KB/segment of L2 reads — negligible.
// A frags: 16 global_load_dwordx4 once per segment (64 VGPR, invariant).
// B frags: 4 loads per kh-phase, 8 per tile. Row partials in registers
// across the segment (R3); col partials per tile; full-64B-line stores.
// ---------------------------------------------------------------------------
template <bool TWO_STAGE>
__global__ __launch_bounds__(256, 3) void gram_kernel(
    const unsigned char* __restrict__ Z,
    float* __restrict__ part, float* __restrict__ S)
{
    // XCD band remap over segments (4224 = 8 * 528), then segment decode.
    const int sid = (blockIdx.x & 7) * (NSEG / 8) + (blockIdx.x >> 3);
    // group g: strips ri = 8g..8g+7 each have v = 32-g segments;
    // cum(g) = 260g - 4g^2 segments before group g.
    int g = (int)((260.0f - sqrtf(67600.0f - 16.0f * (float)sid)) * 0.125f);
    g = g < 0 ? 0 : (g > 31 ? 31 : g);
    while (260 * g - 4 * g * g > sid) --g;
    while (g < 31 && 260 * (g + 1) - 4 * (g + 1) * (g + 1) <= sid) ++g;
    const int local = sid - (260 * g - 4 * g * g);
    const int v  = 32 - g;                 // segments per strip in this group
    const int r8i = local / v;
    const int s4 = local - r8i * v;
    const int ri = 8 * g + r8i;            // row strip 0..255
    const int tj0 = (ri >> 1) + SEGT * s4; // first col tile
    const int nt = (NTILE - tj0 < SEGT) ? (NTILE - tj0) : SEGT;

    const int tid  = threadIdx.x;
    const int w    = tid >> 6;             // wave = col quarter (32 cols)
    const int lane = tid & 63;
    const int lm = lane & 15, lq = lane >> 4;

    // ---- A fragments: global -> regs once per segment. aR[kh][set][fr].
    // lane reads 16B granule pair for rows fr*16+lm, K-slice lq.
    lx2 aR[2][2][4];
    {
        const unsigned char* pa = Z + (size_t)(ri * AT + lm) * DIM + lq * 16;
        #pragma unroll
        for (int fr = 0; fr < 4; ++fr)
            #pragma unroll
            for (int kh = 0; kh < 2; ++kh)
                #pragma unroll
                for (int s = 0; s < 2; ++s)
                    aR[kh][s][fr] =
                        *(const lx2*)(pa + fr * 4096 + kh * 128 + s * 64);
    }

    // ---- B base: rows tj*128 + w*32 + fc*16 + lm, K-slice lq
    const unsigned char* pb =
        Z + (size_t)(tj0 * BT + w * 32 + lm) * DIM + lq * 16;

    const float SC = 2.8853900817779268f / 256.0f;   // exp(2*sim), dot=256*sim

    f32x4 rowacc[4] = {};   // per-lane row partial over this wave's 32 cols

    for (int t = 0; t < nt; ++t) {
        f32x4 acc[4][2] = {};   // [fr][fc]
        #pragma unroll
        for (int kh = 0; kh < 2; ++kh) {
            lx2 bP[2][2];       // [set][fc]
            #pragma unroll
            for (int fc = 0; fc < 2; ++fc)
                #pragma unroll
                for (int s = 0; s < 2; ++s)
                    bP[s][fc] = *(const lx2*)
                        (pb + (size_t)t * 32768 + fc * 4096 + kh * 128 + s * 64);
            #pragma unroll
            for (int s = 0; s < 2; ++s)
                #pragma unroll
                for (int fr = 0; fr < 4; ++fr)
                    #pragma unroll
                    for (int fc = 0; fc < 2; ++fc) {
                        acc[fr][fc] = __builtin_amdgcn_mfma_f32_16x16x32_fp8_fp8(
                            aR[kh][s][fr].x, bP[s][fc].x, acc[fr][fc], 0, 0, 0);
                        acc[fr][fc] = __builtin_amdgcn_mfma_f32_16x16x32_fp8_fp8(
                            aR[kh][s][fr].y, bP[s][fc].y, acc[fr][fc], 0, 0, 0);
                    }
        }

        // ---- per-tile epilogue
        #pragma unroll
        for (int fr = 0; fr < 4; ++fr)
            #pragma unroll
            for (int fc = 0; fc < 2; ++fc)
                #pragma unroll
                for (int r = 0; r < 4; ++r)
                    acc[fr][fc][r] = exp2f(acc[fr][fc][r] * SC);

        const int tj = tj0 + t;
        if (tj == (ri >> 1)) {   // only tile of the segment crossing diagonal
            const int add = (ri & 1) << 6;    // odd strip: rows sit 64 below
            #pragma unroll
            for (int fr = 0; fr < 4; ++fr) {
                const int gi = fr * 16 + lq * 4;
                #pragma unroll
                for (int fc = 0; fc < 2; ++fc) {
                    const int cj = w * 32 + fc * 16 + lm;
                    #pragma unroll
                    for (int r = 0; r < 4; ++r)
                        if (cj <= gi + r + add) acc[fr][fc][r] = 0.0f;
                }
            }
        }

        // row partials: accumulate in registers across the segment
        #pragma unroll
        for (int fr = 0; fr < 4; ++fr)
            #pragma unroll
            for (int r = 0; r < 4; ++r)
                rowacc[fr][r] += acc[fr][0][r] + acc[fr][1][r];

        // col partials per tile: each col owned by exactly one wave
        float* dstc = TWO_STAGE ? (part + (size_t)sid * PSTRIDE + 256 + t * 128)
                                : nullptr;
        #pragma unroll
        for (int fc = 0; fc < 2; ++fc) {
            float s = 0.0f;
            #pragma unroll
            for (int fr = 0; fr < 4; ++fr)
                #pragma unroll
                for (int r = 0; r < 4; ++r) s += acc[fr][fc][r];
            s += __shfl_xor(s, 16, 64);
            s += __shfl_xor(s, 32, 64);
            if (lq == 0) {      // 16 lanes x 4B consecutive = full 64B line
                const int cj = w * 32 + fc * 16 + lm;
                if (TWO_STAGE) dstc[cj] = s;
                else atomicAdd(&S[tj * BT + cj], s);
            }
        }
    }

    // ---- segment epilogue: lane-reduce + store row partials ONCE
    // (4 wave-partials per row; summed in reduce_kernel)
    float* dstr = TWO_STAGE ? (part + (size_t)sid * PSTRIDE) : nullptr;
    #pragma unroll
    for (int fr = 0; fr < 4; ++fr) {
        f32x4 rs;
        #pragma unroll
        for (int r = 0; r < 4; ++r) {
            float s = rowacc[fr][r];
            s += __shfl_xor(s, 1, 64);
            s += __shfl_xor(s, 2, 64);
            s += __shfl_xor(s, 4, 64);
            s += __shfl_xor(s, 8, 64);
            rs[r] = s;
        }
        if (lm == 0) {          // 4 lanes x 16B consecutive = full 64B line
            const int rr = fr * 16 + lq * 4;
            if (TWO_STAGE) *(f32x4*)(dstr + w * 64 + rr) = rs;
            else {
                #pragma unroll
                for (int r = 0; r < 4; ++r)
                    atomicAdd(&S[ri * AT + rr + r], rs[r]);
            }
        }
    }
}

// ---------------------------------------------------------------------------
// Kernel 3: parallel partial gather. grid (NZ/256, NCHUNK).
// Row r: row-side = 4 wave-partials per segment of strip ri=r>>6;
// col-side = 1 entry per strip rip = 0..2*tj+1 hitting col tile tj=r>>7.
// All reads coalesced (64/128-lane runs share ri / tj). Zeroes out[0].
// ---------------------------------------------------------------------------
__global__ __launch_bounds__(256) void reduce_kernel(
    const float* __restrict__ part, float* __restrict__ S2,
    float* __restrict__ out)
{
    const int chunk = blockIdx.y;
    const int tid = threadIdx.x;
    const int r = blockIdx.x * 256 + tid;       // Z row
    const int ri = r >> 6, rr = r & 63;
    const int gg = ri >> 3;
    const int nseg = 32 - gg;
    const int sid0 = 260 * gg - 4 * gg * gg + (ri & 7) * nseg;
    const int tj = r >> 7, cc = r & 127;
    const int nr = 2 * tj + 2;                  // strips covering col tile tj
    const int T = 4 * nseg + nr;

    if (chunk == 0 && r == 0) out[0] = 0.0f;

    float s = 0.0f;
    for (int m = chunk; m < T; m += NCHUNK) {
        size_t addr;
        if (m < 4 * nseg) {
            addr = (size_t)(sid0 + (m >> 2)) * PSTRIDE + (m & 3) * 64 + rr;
        } else {
            const int rip = m - 4 * nseg;       // source strip
            const int dtj = tj - (rip >> 1);
            const int gp = rip >> 3;
            const int sidc = 260 * gp - 4 * gp * gp + (rip & 7) * (32 - gp)
                           + (dtj >> 2);
            addr = (size_t)sidc * PSTRIDE + 256 + (dtj & 3) * 128 + cc;
        }
        s += part[addr];
    }
    S2[(size_t)chunk * NZ + r] = s;
}

// ---------------------------------------------------------------------------
// Kernel 4: loss + mean (two-stage path).
// ---------------------------------------------------------------------------
__global__ __launch_bounds__(256) void loss2_kernel(
    const float* __restrict__ S2, const float* __restrict__ pos,
    float* __restrict__ out)
{
    const int i = blockIdx.x * 256 + threadIdx.x;
    float den1 = 0.0f, den2 = 0.0f;
    #pragma unroll
    for (int c = 0; c < NCHUNK; ++c) {
        den1 += S2[(size_t)c * NZ + i];
        den2 += S2[(size_t)c * NZ + N_ROWS + i];
    }
    float v = 0.5f * (logf(den1) + logf(den2)) - TAU_INV * pos[i];

    __shared__ float red[4];
    #pragma unroll
    for (int m = 1; m < 64; m <<= 1) v += __shfl_xor(v, m, 64);
    if ((threadIdx.x & 63) == 0) red[threadIdx.x >> 6] = v;
    __syncthreads();
    if (threadIdx.x == 0)
        atomicAdd(out, (red[0] + red[1] + red[2] + red[3]) * (1.0f / N_ROWS));
}

// Fallback loss (atomic path, only if ws too small — never expected).
__global__ __launch_bounds__(256) void loss_kernel(
    const float* __restrict__ S, const float* __restrict__ pos,
    float* __restrict__ out)
{
    const int i = blockIdx.x * 256 + threadIdx.x;
    float v = 0.5f * (logf(S[i]) + logf(S[N_ROWS + i])) - TAU_INV * pos[i];

    __shared__ float red[4];
    #pragma unroll
    for (int m = 1; m < 64; m <<= 1) v += __shfl_xor(v, m, 64);
    if ((threadIdx.x & 63) == 0) red[threadIdx.x >> 6] = v;
    __syncthreads();
    if (threadIdx.x == 0)
        atomicAdd(out, (red[0] + red[1] + red[2] + red[3]) * (1.0f / N_ROWS));
}

// ---------------------------------------------------------------------------
extern "C" void kernel_launch(void* const* d_in, const int* in_sizes, int n_in,
                              void* d_out, int out_size, void* d_ws, size_t ws_size,
                              hipStream_t stream)
{
    const float* z1 = (const float*)d_in[0];
    const float* z2 = (const float*)d_in[1];
    float* out = (float*)d_out;

    char* ws = (char*)d_ws;
    unsigned char* Z8 = (unsigned char*)ws;              // 16384*256 = 4 MB
    float* pos  = (float*)(ws + 4194304);                // 32 KB
    float* S2   = (float*)(ws + 4227072);                // 16*16384*4 = 1 MB
    float* part = (float*)(ws + 5275648);                // 4224*768*4 = 13 MB
    const size_t need = 5275648 + (size_t)NSEG * PSTRIDE * 4;

    normalize_kernel<<<N_ROWS / 4, 256, 0, stream>>>(z1, z2, Z8, pos);

    if (ws_size >= need) {
        gram_kernel<true><<<NSEG, 256, 0, stream>>>(Z8, part, nullptr);
        dim3 rg(NZ / 256, NCHUNK);
        reduce_kernel<<<rg, 256, 0, stream>>>(part, S2, out);   // zeroes out
        loss2_kernel<<<N_ROWS / 256, 256, 0, stream>>>(S2, pos, out);
    } else {
        hipMemsetAsync(S2, 0, NZ * sizeof(float), stream);
        hipMemsetAsync(out, 0, sizeof(float), stream);
        gram_kernel<false><<<NSEG, 256, 0, stream>>>(Z8, nullptr, S2);
        loss_kernel<<<N_ROWS / 256, 256, 0, stream>>>(S2, pos, out);
    }
}

// Round 6
// 160.588 us; speedup vs baseline: 1.1586x; 1.1586x over previous
//
#include <hip/hip_runtime.h>
#include <hip/hip_bf16.h>
#include <hip/hip_fp8.h>

#define N_ROWS 8192
#define NZ 16384           // rows of Z = [An; Bn]
#define DIM 256
#define TAU_INV 2.0f
#define BT 128             // col tile width
#define AT 64              // row tile height (A strip)
#define NTILE 128          // NZ / BT  (col tiles)
#define NCHUNK 16
#define SEGT 4             // col tiles per segment
#define NSEG 4224          // sum over ri of ceil((128 - (ri>>1))/4)
#define PSTRIDE 768        // floats/segment: 4*64 row-partials + 4*128 col-partials

typedef float f32x4 __attribute__((ext_vector_type(4)));
typedef long lx2 __attribute__((ext_vector_type(2)));   // 16B = 2 fp8 MFMA operands

// ---------------------------------------------------------------------------
// Kernel 1: one WAVE per row. L2-normalize, scale by 16, quantize to OCP fp8
// e4m3, write Z8 K-INTERLEAVED: each 64B chunk stores its eight 8B K-groups
// as [g0 g4 g1 g5 g2 g6 g3 g7] so one 16B granule = operand pair (g, g+4)
// for two consecutive MFMA K-steps. pos[i] = (1/256)*dot(quantized an, bn).
// ---------------------------------------------------------------------------
__global__ __launch_bounds__(256) void normalize_kernel(
    const float* __restrict__ z1, const float* __restrict__ z2,
    unsigned char* __restrict__ Z8, float* __restrict__ pos)
{
    const int tid = threadIdx.x;
    const int wave = tid >> 6;
    const int lane = tid & 63;
    const int row = blockIdx.x * 4 + wave;      // 0..8191

    const float4 a = ((const float4*)(z1 + (size_t)row * DIM))[lane];
    const float4 b = ((const float4*)(z2 + (size_t)row * DIM))[lane];

    auto wsum = [&](float v) -> float {
        #pragma unroll
        for (int m = 1; m < 64; m <<= 1) v += __shfl_xor(v, m, 64);
        return v;
    };

    const float na2 = wsum(a.x*a.x + a.y*a.y + a.z*a.z + a.w*a.w);
    const float nb2 = wsum(b.x*b.x + b.y*b.y + b.z*b.z + b.w*b.w);
    const float sa = 16.0f / sqrtf(na2);   // norms ~16; eps never binds
    const float sb = 16.0f / sqrtf(nb2);

    const float av[4] = {a.x*sa, a.y*sa, a.z*sa, a.w*sa};
    const float bv[4] = {b.x*sb, b.y*sb, b.z*sb, b.w*sb};
    unsigned char pa[4], pb[4];
    float qd = 0.0f;
    #pragma unroll
    for (int k = 0; k < 4; ++k) {
        __hip_fp8_e4m3 qa(av[k]);
        __hip_fp8_e4m3 qb(bv[k]);
        pa[k] = qa.__x; pb[k] = qb.__x;
        qd += float(qa) * float(qb);
    }
    const int g  = (lane >> 1) & 7;
    const int pp = ((g & 3) << 1) | (g >> 2);          // interleaved 8B slot
    const int off = (lane >> 4) * 64 + pp * 8 + (lane & 1) * 4;
    *(uchar4*)(Z8 + (size_t)row * DIM + off) = *(uchar4*)pa;
    *(uchar4*)(Z8 + (size_t)(N_ROWS + row) * DIM + off) = *(uchar4*)pb;

    qd = wsum(qd);
    if (lane == 0) pos[row] = qd * 0.00390625f;   // /256 -> quantized sim
}

// ---------------------------------------------------------------------------
// Kernel 2: symmetric fp8 gram, 64x128 tiles, strip-segmented, BARRIER-FREE
// WAVE-PRIVATE PIPELINE (R6 = R4+R5 synthesis):
//  - 1x4 wave layout: wave w owns all 64 A rows x cols w*32..w*32+31. Its B
//    rows are touched by NO other wave -> B staged into wave-PRIVATE LDS
//    (3-slot x 4KB ring per wave) -> zero __syncthreads in the whole kernel.
//  - Counted-vmcnt pipeline (T3/T4 without barriers): phase p issues
//    stage(p+2), waits vmcnt(8) (stage p drained, stage p+1 STAYS IN FLIGHT),
//    never vmcnt(0) until the tail. Loop has NO other VMEM ops (col partials
//    deferred to registers), so the counts are exact.
//  - B ds_reads are inline asm (prevents compiler's conservative
//    global_load_lds<->ds_read ordering) + lgkmcnt(0) + sched_barrier(0)
//    (rule #18). The lgkm fence also makes slot-reuse WAR safe: a slot is
//    re-staged only after the fence that retired its reads.
//  - LDS XOR swizzle: granule gi of row rl stored at slot gi^(rl&7)
//    (pre-swizzled global src, linear gload_lds dest; read applies same XOR)
//    -> 8 lanes/bank-quad uniform, conflict-free ds_read_b128.
//  - A fragments global->VGPR once per segment (64 VGPR, R5-proven layout).
//  - Fixed 4-tile unroll with clamped tail (toff=min(t,nt-1)); t>=nt tiles
//    compute on duplicate data, accumulation skipped -> all array indices
//    compile-time (rule #20), vmcnt schedule static.
// LDS 48KB -> 3 blocks/CU (12 waves/CU).
// ---------------------------------------------------------------------------
#define MFMA8(A, B, C) __builtin_amdgcn_mfma_f32_16x16x32_fp8_fp8(A, B, C, 0, 0, 0)

#define STAGE(TF, KH, SL)                                                      \
  { const unsigned char* gsrc = pb0 + (size_t)(TF) * 32768 + (KH) * 128;       \
    _Pragma("unroll")                                                          \
    for (int c = 0; c < 4; ++c)                                                \
      __builtin_amdgcn_global_load_lds(                                        \
        (const __attribute__((address_space(1))) void*)(gsrc + c * 2048),      \
        (__attribute__((address_space(3))) void*)(Ls + wvLds + (SL)*4096 + c*1024), \
        16, 0, 0); }

#define MFMA_HALF(KH)                                                          \
  __builtin_amdgcn_s_setprio(1);                                               \
  _Pragma("unroll")                                                            \
  for (int fr = 0; fr < 4; ++fr) {                                             \
    acc[fr][0] = MFMA8(aR[KH][0][fr].x, b00.x, acc[fr][0]);                    \
    acc[fr][0] = MFMA8(aR[KH][0][fr].y, b00.y, acc[fr][0]);                    \
    acc[fr][1] = MFMA8(aR[KH][0][fr].x, b10.x, acc[fr][1]);                    \
    acc[fr][1] = MFMA8(aR[KH][0][fr].y, b10.y, acc[fr][1]);                    \
  }                                                                            \
  _Pragma("unroll")                                                            \
  for (int fr = 0; fr < 4; ++fr) {                                             \
    acc[fr][0] = MFMA8(aR[KH][1][fr].x, b01.x, acc[fr][0]);                    \
    acc[fr][0] = MFMA8(aR[KH][1][fr].y, b01.y, acc[fr][0]);                    \
    acc[fr][1] = MFMA8(aR[KH][1][fr].x, b11.x, acc[fr][1]);                    \
    acc[fr][1] = MFMA8(aR[KH][1][fr].y, b11.y, acc[fr][1]);                    \
  }

#define PHASE(KH, SLOT, NW, DOISS, TF2, KH2, SLOT2)                            \
  {                                                                            \
    if (DOISS) STAGE(TF2, KH2, SLOT2);                                         \
    asm volatile("s_waitcnt vmcnt(" #NW ")" ::: "memory");                     \
    lx2 b00, b10, b01, b11;                                                    \
    asm volatile("ds_read_b128 %0, %1" : "=v"(b00) : "v"(bA00 + (SLOT)*4096)); \
    asm volatile("ds_read_b128 %0, %1" : "=v"(b10) : "v"(bA10 + (SLOT)*4096)); \
    asm volatile("ds_read_b128 %0, %1" : "=v"(b01) : "v"(bA01 + (SLOT)*4096)); \
    asm volatile("ds_read_b128 %0, %1" : "=v"(b11) : "v"(bA11 + (SLOT)*4096)); \
    asm volatile("s_waitcnt lgkmcnt(0)" ::: "memory");                         \
    __builtin_amdgcn_sched_barrier(0);                                         \
    MFMA_HALF(KH)                                                              \
    __builtin_amdgcn_s_setprio(0);                                             \
  }

#define EPILOG(T)                                                              \
  if ((T) < nt) {                                                              \
    _Pragma("unroll")                                                          \
    for (int fr = 0; fr < 4; ++fr)                                             \
      _Pragma("unroll")                                                        \
      for (int fc = 0; fc < 2; ++fc)                                           \
        _Pragma("unroll")                                                      \
        for (int r = 0; r < 4; ++r)                                            \
          acc[fr][fc][r] = exp2f(acc[fr][fc][r] * SC);                         \
    if ((T) == 0 && s4 == 0) {                                                 \
      const int add = (ri & 1) << 6;                                           \
      _Pragma("unroll")                                                        \
      for (int fr = 0; fr < 4; ++fr) {                                         \
        const int gi = fr * 16 + lq * 4;                                       \
        _Pragma("unroll")                                                      \
        for (int fc = 0; fc < 2; ++fc) {                                       \
          const int cj = wv * 32 + fc * 16 + lm;                               \
          _Pragma("unroll")                                                    \
          for (int r = 0; r < 4; ++r)                                          \
            if (cj <= gi + r + add) acc[fr][fc][r] = 0.0f;                     \
        }                                                                      \
      }                                                                        \
    }                                                                          \
    _Pragma("unroll")                                                          \
    for (int fr = 0; fr < 4; ++fr)                                             \
      _Pragma("unroll")                                                        \
      for (int r = 0; r < 4; ++r)                                              \
        rowacc[fr][r] += acc[fr][0][r] + acc[fr][1][r];                        \
    _Pragma("unroll")                                                          \
    for (int fc = 0; fc < 2; ++fc) {                                           \
      float s_ = 0.0f;                                                         \
      _Pragma("unroll")                                                        \
      for (int fr = 0; fr < 4; ++fr)                                           \
        _Pragma("unroll")                                                      \
        for (int r = 0; r < 4; ++r) s_ += acc[fr][fc][r];                      \
      colacc[T][fc] = s_;                                                      \
    }                                                                          \
  }

template <bool TWO_STAGE>
__global__ __launch_bounds__(256, 3) void gram_kernel(
    const unsigned char* __restrict__ Z,
    float* __restrict__ part, float* __restrict__ S)
{
    // XCD band remap over segments (4224 = 8 * 528), then segment decode.
    const int sid = (blockIdx.x & 7) * (NSEG / 8) + (blockIdx.x >> 3);
    int g = (int)((260.0f - sqrtf(67600.0f - 16.0f * (float)sid)) * 0.125f);
    g = g < 0 ? 0 : (g > 31 ? 31 : g);
    while (260 * g - 4 * g * g > sid) --g;
    while (g < 31 && 260 * (g + 1) - 4 * (g + 1) * (g + 1) <= sid) ++g;
    const int local = sid - (260 * g - 4 * g * g);
    const int v  = 32 - g;                 // segments per strip in this group
    const int r8i = local / v;
    const int s4 = local - r8i * v;
    const int ri = 8 * g + r8i;            // row strip 0..255
    const int tj0 = (ri >> 1) + SEGT * s4; // first col tile
    const int nt = (NTILE - tj0 < SEGT) ? (NTILE - tj0) : SEGT;
    const int tf1 = nt > 1 ? 1 : 0;        // clamped tile offsets (tail dup)
    const int tf2 = nt > 2 ? 2 : tf1;
    const int tf3 = nt > 3 ? 3 : tf2;

    __shared__ unsigned char Ls[49152];    // 4 waves x 3 slots x 4KB, private

    const int tid  = threadIdx.x;
    const int wv   = tid >> 6;             // wave = col quarter (32 cols)
    const int lane = tid & 63;
    const int lm = lane & 15, lq = lane >> 4;
    const unsigned wvLds = wv * 12288;

    // ---- A fragments: global -> regs once per segment (R5-proven layout)
    lx2 aR[2][2][4];
    {
        const unsigned char* pa = Z + (size_t)(ri * AT + lm) * DIM + lq * 16;
        #pragma unroll
        for (int fr = 0; fr < 4; ++fr)
            #pragma unroll
            for (int kh = 0; kh < 2; ++kh)
                #pragma unroll
                for (int s = 0; s < 2; ++s)
                    aR[kh][s][fr] =
                        *(const lx2*)(pa + fr * 4096 + kh * 128 + s * 64);
    }

    // ---- staging lane geometry: 1KB chunk = 8 rows x 8 granules(16B).
    // LDS dest is linear (lane*16); global src pre-swizzled: granule g7^l8
    // so that LDS[row rl][slot q] holds global granule q^(rl&7).
    const int l8 = lane >> 3;
    const int g7 = lane & 7;
    const unsigned char* pb0 =
        Z + (size_t)(tj0 * BT + wv * 32 + l8) * DIM + ((g7 ^ l8) << 4);

    // ---- swizzled ds_read addresses (row rl=fc*16+lm, granule gi=s*4+lq
    // at slot gi^(lm&7)): conflict-free (8 lanes per bank-quad, uniform)
    const unsigned ldsBase = (unsigned)(unsigned long long)
        (__attribute__((address_space(3))) unsigned char*)Ls;
    const unsigned wvB = ldsBase + wvLds + (unsigned)(lm * 128);
    const unsigned q0 = (unsigned)(((lq    ) ^ (lm & 7)) << 4);
    const unsigned q1 = (unsigned)(((lq + 4) ^ (lm & 7)) << 4);
    const unsigned bA00 = wvB + q0;           // fc0,s0
    const unsigned bA01 = wvB + q1;           // fc0,s1
    const unsigned bA10 = wvB + 2048 + q0;    // fc1,s0
    const unsigned bA11 = wvB + 2048 + q1;    // fc1,s1

    const float SC = 2.8853900817779268f / 256.0f;   // exp(2*sim), dot=256*sim

    f32x4 rowacc[4] = {};      // per-lane row partials over segment
    float colacc[4][2] = {};   // per-lane col partials per tile (static idx)

    // ---- prologue: fill pipeline 2 phases deep
    STAGE(0, 0, 0)
    STAGE(0, 1, 1)

    // ---- 8 phases (4 tiles x 2 K-halves), slot = phase % 3, all static
    { f32x4 acc[4][2] = {};
      PHASE(0, 0, 8, 1, tf1, 0, 2)
      PHASE(1, 1, 8, 1, tf1, 1, 0)
      EPILOG(0)
    }
    { f32x4 acc[4][2] = {};
      PHASE(0, 2, 8, 1, tf2, 0, 1)
      PHASE(1, 0, 8, 1, tf2, 1, 2)
      EPILOG(1)
    }
    { f32x4 acc[4][2] = {};
      PHASE(0, 1, 8, 1, tf3, 0, 0)
      PHASE(1, 2, 8, 1, tf3, 1, 1)
      EPILOG(2)
    }
    { f32x4 acc[4][2] = {};
      PHASE(0, 0, 4, 0, 0, 0, 0)
      PHASE(1, 1, 0, 0, 0, 0, 0)
      EPILOG(3)
    }

    // ---- segment-end: cross-lane reduce + stores (all VMEM drained above)
    #pragma unroll
    for (int t = 0; t < 4; ++t)
        #pragma unroll
        for (int fc = 0; fc < 2; ++fc) {
            float s = colacc[t][fc];
            s += __shfl_xor(s, 16, 64);
            s += __shfl_xor(s, 32, 64);
            if (lq == 0) {      // 16 lanes x 4B consecutive = full 64B line
                const int cj = wv * 32 + fc * 16 + lm;
                if (TWO_STAGE)
                    part[(size_t)sid * PSTRIDE + 256 + t * 128 + cj] = s;
                else if (t < nt)
                    atomicAdd(&S[(tj0 + t) * BT + cj], s);
            }
        }

    float* dstr = TWO_STAGE ? (part + (size_t)sid * PSTRIDE) : nullptr;
    #pragma unroll
    for (int fr = 0; fr < 4; ++fr) {
        f32x4 rs;
        #pragma unroll
        for (int r = 0; r < 4; ++r) {
            float s = rowacc[fr][r];
            s += __shfl_xor(s, 1, 64);
            s += __shfl_xor(s, 2, 64);
            s += __shfl_xor(s, 4, 64);
            s += __shfl_xor(s, 8, 64);
            rs[r] = s;
        }
        if (lm == 0) {          // 4 lanes x 16B consecutive = full 64B line
            const int rr = fr * 16 + lq * 4;
            if (TWO_STAGE) *(f32x4*)(dstr + wv * 64 + rr) = rs;
            else {
                #pragma unroll
                for (int r = 0; r < 4; ++r)
                    atomicAdd(&S[ri * AT + rr + r], rs[r]);
            }
        }
    }
}

// ---------------------------------------------------------------------------
// Kernel 3: parallel partial gather. grid (NZ/256, NCHUNK).
// Row r: row-side = 4 wave-partials per segment of strip ri=r>>6;
// col-side = 1 entry per strip rip = 0..2*tj+1 hitting col tile tj=r>>7.
// All reads coalesced (64/128-lane runs share ri / tj). Zeroes out[0].
// ---------------------------------------------------------------------------
__global__ __launch_bounds__(256) void reduce_kernel(
    const float* __restrict__ part, float* __restrict__ S2,
    float* __restrict__ out)
{
    const int chunk = blockIdx.y;
    const int tid = threadIdx.x;
    const int r = blockIdx.x * 256 + tid;       // Z row
    const int ri = r >> 6, rr = r & 63;
    const int gg = ri >> 3;
    const int nseg = 32 - gg;
    const int sid0 = 260 * gg - 4 * gg * gg + (ri & 7) * nseg;
    const int tj = r >> 7, cc = r & 127;
    const int nr = 2 * tj + 2;                  // strips covering col tile tj
    const int T = 4 * nseg + nr;

    if (chunk == 0 && r == 0) out[0] = 0.0f;

    float s = 0.0f;
    for (int m = chunk; m < T; m += NCHUNK) {
        size_t addr;
        if (m < 4 * nseg) {
            addr = (size_t)(sid0 + (m >> 2)) * PSTRIDE + (m & 3) * 64 + rr;
        } else {
            const int rip = m - 4 * nseg;       // source strip
            const int dtj = tj - (rip >> 1);
            const int gp = rip >> 3;
            const int sidc = 260 * gp - 4 * gp * gp + (rip & 7) * (32 - gp)
                           + (dtj >> 2);
            addr = (size_t)sidc * PSTRIDE + 256 + (dtj & 3) * 128 + cc;
        }
        s += part[addr];
    }
    S2[(size_t)chunk * NZ + r] = s;
}

// ---------------------------------------------------------------------------
// Kernel 4: loss + mean (two-stage path).
// ---------------------------------------------------------------------------
__global__ __launch_bounds__(256) void loss2_kernel(
    const float* __restrict__ S2, const float* __restrict__ pos,
    float* __restrict__ out)
{
    const int i = blockIdx.x * 256 + threadIdx.x;
    float den1 = 0.0f, den2 = 0.0f;
    #pragma unroll
    for (int c = 0; c < NCHUNK; ++c) {
        den1 += S2[(size_t)c * NZ + i];
        den2 += S2[(size_t)c * NZ + N_ROWS + i];
    }
    float v = 0.5f * (logf(den1) + logf(den2)) - TAU_INV * pos[i];

    __shared__ float red[4];
    #pragma unroll
    for (int m = 1; m < 64; m <<= 1) v += __shfl_xor(v, m, 64);
    if ((threadIdx.x & 63) == 0) red[threadIdx.x >> 6] = v;
    __syncthreads();
    if (threadIdx.x == 0)
        atomicAdd(out, (red[0] + red[1] + red[2] + red[3]) * (1.0f / N_ROWS));
}

// Fallback loss (atomic path, only if ws too small — never expected).
__global__ __launch_bounds__(256) void loss_kernel(
    const float* __restrict__ S, const float* __restrict__ pos,
    float* __restrict__ out)
{
    const int i = blockIdx.x * 256 + threadIdx.x;
    float v = 0.5f * (logf(S[i]) + logf(S[N_ROWS + i])) - TAU_INV * pos[i];

    __shared__ float red[4];
    #pragma unroll
    for (int m = 1; m < 64; m <<= 1) v += __shfl_xor(v, m, 64);
    if ((threadIdx.x & 63) == 0) red[threadIdx.x >> 6] = v;
    __syncthreads();
    if (threadIdx.x == 0)
        atomicAdd(out, (red[0] + red[1] + red[2] + red[3]) * (1.0f / N_ROWS));
}

// ---------------------------------------------------------------------------
extern "C" void kernel_launch(void* const* d_in, const int* in_sizes, int n_in,
                              void* d_out, int out_size, void* d_ws, size_t ws_size,
                              hipStream_t stream)
{
    const float* z1 = (const float*)d_in[0];
    const float* z2 = (const float*)d_in[1];
    float* out = (float*)d_out;

    char* ws = (char*)d_ws;
    unsigned char* Z8 = (unsigned char*)ws;              // 16384*256 = 4 MB
    float* pos  = (float*)(ws + 4194304);                // 32 KB
    float* S2   = (float*)(ws + 4227072);                // 16*16384*4 = 1 MB
    float* part = (float*)(ws + 5275648);                // 4224*768*4 = 13 MB
    const size_t need = 5275648 + (size_t)NSEG * PSTRIDE * 4;

    normalize_kernel<<<N_ROWS / 4, 256, 0, stream>>>(z1, z2, Z8, pos);

    if (ws_size >= need) {
        gram_kernel<true><<<NSEG, 256, 0, stream>>>(Z8, part, nullptr);
        dim3 rg(NZ / 256, NCHUNK);
        reduce_kernel<<<rg, 256, 0, stream>>>(part, S2, out);   // zeroes out
        loss2_kernel<<<N_ROWS / 256, 256, 0, stream>>>(S2, pos, out);
    } else {
        hipMemsetAsync(S2, 0, NZ * sizeof(float), stream);
        hipMemsetAsync(out, 0, sizeof(float), stream);
        gram_kernel<false><<<NSEG, 256, 0, stream>>>(Z8, nullptr, S2);
        loss_kernel<<<N_ROWS / 256, 256, 0, stream>>>(S2, pos, out);
    }
}